// Round 5
// baseline (852.938 us; speedup 1.0000x reference)
//
#include <hip/hip_runtime.h>
#include <stdint.h>

#define T_STEPS 100
#define D_IN 16
#define H_DIM 32
#define HD 50
#define KXH 48
#define EULER 10
#define STEPF 0.1f
#define DT_SCALERF (1.0f/24.0f)
#define TANH_SCALE 2.8853900817779268f   // 2*log2(e), folded into W1/W2/W3 + biases

typedef __attribute__((ext_vector_type(8))) short short8;
typedef __attribute__((ext_vector_type(4))) float float4v;
typedef __attribute__((ext_vector_type(2))) uint32_t uint2v;
typedef __attribute__((ext_vector_type(4))) uint32_t uint4v;

// input prescaled by 2*log2(e): tanh(u) = 1 - 2/(exp2(us)+1)
__device__ __forceinline__ float tanh_pre(float us) {
    float e = __builtin_amdgcn_exp2f(us);
    return 1.0f - 2.0f * __builtin_amdgcn_rcpf(e + 1.0f);
}
__device__ __forceinline__ uint32_t f2bf_u(float f) {
    uint32_t u = __builtin_bit_cast(uint32_t, f);
    return u + 0x7fffu + ((u >> 16) & 1u);   // RNE
}
__device__ __forceinline__ uint32_t pack2(float lo, float hi) {
    // hi16(rnd(hi)) : hi16(rnd(lo)) via v_perm_b32
    return __builtin_amdgcn_perm(f2bf_u(hi), f2bf_u(lo), 0x07060302u);
}
__device__ __forceinline__ short f2bf(float f) { return (short)(f2bf_u(f) >> 16); }

// 3-wave block, 16 batch. Wave 0 ("h-wave") runs the ENTIRE h-recurrence
// (u1 -> z -> u2 -> h) self-contained: its LDS transposes are self-write ->
// self-read (in-order DS pipe, no barriers needed). Waves 1,2 ("dy-waves")
// compute u3/dy from hbuf (double-buffered by euler parity), 1 barrier per
// Euler step. dy partials merge with lag-1 so y never blocks the h-wave.
__global__ __launch_bounds__(192) void latode_kernel(
    const float* __restrict__ dt, const float* __restrict__ x,
    const float* __restrict__ W1, const float* __restrict__ b1,
    const float* __restrict__ W2, const float* __restrict__ b2,
    const float* __restrict__ W3, const float* __restrict__ b3,
    const float* __restrict__ W4, const float* __restrict__ b4,
    float* __restrict__ out)
{
    const int tid  = threadIdx.x;
    const int wave = tid >> 6;
    const int lane = tid & 63;
    const int n16  = lane & 15;       // batch column
    const int quad = lane >> 4;
    const int b0   = blockIdx.x * 16;

    __shared__ __align__(16) uint32_t hbuf[2][16 * 20]; // [par][batch][feat-pair], stride 20 dw
    __shared__ __align__(16) uint32_t zbuf[16 * 36];    // h-wave private   [batch][feat-pair]
    __shared__ float pbuf[2][2][16];                    // [par][dy-wave][batch]

    // zero-init LDS (harness poisons 0xAA)
    for (int i = tid; i < 2 * 16 * 20; i += 192) ((uint32_t*)hbuf)[i] = 0;
    for (int i = tid; i < 16 * 36; i += 192) zbuf[i] = 0;
    if (tid < 64) ((float*)pbuf)[tid] = 0.0f;
    __syncthreads();

    const float b4s = b4[0];

    if (wave == 0) {
        // ================= h-wave: full h-recurrence, barrier-independent ==========
        short8 w1f[4][2];
#pragma unroll
        for (int mt = 0; mt < 4; ++mt) {
            int m = mt * 16 + n16;
#pragma unroll
            for (int kt = 0; kt < 2; ++kt)
#pragma unroll
                for (int j = 0; j < 8; ++j) {
                    int kk = kt * 32 + quad * 8 + j;   // K remap: [h(0..31)|x(32..47)|pad]
                    float w = 0.0f;
                    if (m < HD) {
                        if (kk < 32)      w = W1[m * KXH + 16 + kk];
                        else if (kk < 48) w = W1[m * KXH + (kk - 32)];
                    }
                    w1f[mt][kt][j] = f2bf(w * TANH_SCALE);
                }
        }
        short8 w2f[2][2];
#pragma unroll
        for (int mt = 0; mt < 2; ++mt) {
            int m = mt * 16 + n16;
#pragma unroll
            for (int kt = 0; kt < 2; ++kt)
#pragma unroll
                for (int j = 0; j < 8; ++j) {
                    int kk = kt * 32 + quad * 8 + j;
                    w2f[mt][kt][j] = f2bf(kk < HD ? W2[m * HD + kk] * TANH_SCALE : 0.0f);
                }
        }
        float4v b1v[4], b2v[2];
#pragma unroll
        for (int mt = 0; mt < 4; ++mt)
#pragma unroll
            for (int r = 0; r < 4; ++r) {
                int f = mt * 16 + quad * 4 + r;
                b1v[mt][r] = (f < HD) ? b1[f] * TANH_SCALE : 0.0f;
            }
#pragma unroll
        for (int mt = 0; mt < 2; ++mt)
#pragma unroll
            for (int r = 0; r < 4; ++r)
                b2v[mt][r] = b2[mt * 16 + quad * 4 + r] * TANH_SCALE;

        float4v hC[2];
        hC[0] = (float4v){0.f, 0.f, 0.f, 0.f};
        hC[1] = (float4v){0.f, 0.f, 0.f, 0.f};

        const float* xrow = x + (size_t)(b0 + n16) * (T_STEPS * D_IN);
        const float* drow = dt + (size_t)(b0 + n16) * (T_STEPS * 2);
        float4 xa = {0,0,0,0}, xb = {0,0,0,0};
        if (quad < 2) {
            xa = *(const float4*)(xrow + quad * 8);
            xb = *(const float4*)(xrow + quad * 8 + 4);
        }
        float2 dtv = *(const float2*)(drow);

#pragma unroll 1
        for (int t = 0; t < T_STEPS; ++t) {
            short8 xB = (short8){0,0,0,0,0,0,0,0};
            if (quad < 2) {
                uint4v xp;
                xp[0] = pack2(xa.x, xa.y); xp[1] = pack2(xa.z, xa.w);
                xp[2] = pack2(xb.x, xb.y); xp[3] = pack2(xb.z, xb.w);
                xB = __builtin_bit_cast(short8, xp);
            }
            const float s10 = STEPF * ((dtv.y - dtv.x) * DT_SCALERF);  // per batch n16

            { // prefetch t+1
                int tn = (t + 1 < T_STEPS) ? t + 1 : (T_STEPS - 1);
                if (quad < 2) {
                    xa = *(const float4*)(xrow + tn * D_IN + quad * 8);
                    xb = *(const float4*)(xrow + tn * D_IN + quad * 8 + 4);
                }
                dtv = *(const float2*)(drow + tn * 2);
            }

#pragma unroll 1
            for (int e = 0; e < EULER; ++e) {
                const int par = e & 1;
                // h-frag: self round-trip (written at e-1 / init)
                short8 hB = __builtin_bit_cast(short8, *(const uint4v*)&hbuf[par][n16 * 20 + quad * 4]);

                // u1: 4 tiles x 2 K-MFMA
                float4v a1[4];
#pragma unroll
                for (int mt = 0; mt < 4; ++mt) {
                    a1[mt] = b1v[mt];
                    a1[mt] = __builtin_amdgcn_mfma_f32_16x16x32_bf16(w1f[mt][0], hB, a1[mt], 0, 0, 0);
                    a1[mt] = __builtin_amdgcn_mfma_f32_16x16x32_bf16(w1f[mt][1], xB, a1[mt], 0, 0, 0);
                }
                // z = tanh(u1) -> zbuf (tiles 0-2 full; tile 3 only feats 48,49)
#pragma unroll
                for (int mt = 0; mt < 3; ++mt) {
                    float z0 = tanh_pre(a1[mt][0]), z1 = tanh_pre(a1[mt][1]);
                    float z2 = tanh_pre(a1[mt][2]), z3 = tanh_pre(a1[mt][3]);
                    *(uint2v*)&zbuf[n16 * 36 + mt * 8 + quad * 2] =
                        (uint2v){pack2(z0, z1), pack2(z2, z3)};
                }
                {
                    float z0 = tanh_pre(a1[3][0]), z1 = tanh_pre(a1[3][1]);
                    if (quad == 0) zbuf[n16 * 36 + 24] = pack2(z0, z1);
                }
                // u2
                short8 zB0 = __builtin_bit_cast(short8, *(const uint4v*)&zbuf[n16 * 36 + quad * 4]);
                short8 zB1 = __builtin_bit_cast(short8, *(const uint4v*)&zbuf[n16 * 36 + 16 + quad * 4]);
#pragma unroll
                for (int mt = 0; mt < 2; ++mt) {
                    float4v u2 = b2v[mt];
                    u2 = __builtin_amdgcn_mfma_f32_16x16x32_bf16(w2f[mt][0], zB0, u2, 0, 0, 0);
                    u2 = __builtin_amdgcn_mfma_f32_16x16x32_bf16(w2f[mt][1], zB1, u2, 0, 0, 0);
                    hC[mt][0] += s10 * tanh_pre(u2[0]);
                    hC[mt][1] += s10 * tanh_pre(u2[1]);
                    hC[mt][2] += s10 * tanh_pre(u2[2]);
                    hC[mt][3] += s10 * tanh_pre(u2[3]);
                }
                // publish h(e+1) into the other parity buffer
                *(uint2v*)&hbuf[1 - par][n16 * 20 + 0 + quad * 2] =
                    (uint2v){pack2(hC[0][0], hC[0][1]), pack2(hC[0][2], hC[0][3])};
                *(uint2v*)&hbuf[1 - par][n16 * 20 + 8 + quad * 2] =
                    (uint2v){pack2(hC[1][0], hC[1][1]), pack2(hC[1][2], hC[1][3])};
                __syncthreads();
            } // e
        } // t
        __syncthreads();   // final (matches dy-path)
    } else {
        // ================= dy-waves: u3 tiles, partials, lag-1 y merge ============
        const int half = wave - 1;            // tiles 2*half, 2*half+1
        short8 w3f[2];
        float4v b3v[2], w4v[2];
#pragma unroll
        for (int k = 0; k < 2; ++k) {
            int mt = half * 2 + k;
            int m = mt * 16 + n16;
#pragma unroll
            for (int j = 0; j < 8; ++j)
                w3f[k][j] = f2bf(W3[m * H_DIM + quad * 8 + j] * TANH_SCALE);
#pragma unroll
            for (int r = 0; r < 4; ++r) {
                int f = mt * 16 + quad * 4 + r;
                b3v[k][r] = b3[f] * TANH_SCALE;
                w4v[k][r] = W4[f];
            }
        }
        // wave 1 owns the y path
        const float* drow = dt + (size_t)(b0 + n16) * (T_STEPS * 2);
        const float* xrow = x + (size_t)(b0 + n16) * (T_STEPS * D_IN);
        float2 dtv = {0.f, 0.f};
        float y0c = 0.f;
        if (wave == 1) { dtv = *(const float2*)(drow); y0c = xrow[0]; }
        float psum = 0.f, prev_scl = 0.f, prev_y0 = 0.f;

#pragma unroll 1
        for (int t = 0; t < T_STEPS; ++t) {
            const float cur_scl = (dtv.y - dtv.x) * DT_SCALERF;
            const float cur_y0  = y0c;
            if (wave == 1) { // prefetch t+1
                int tn = (t + 1 < T_STEPS) ? t + 1 : (T_STEPS - 1);
                dtv = *(const float2*)(drow + tn * 2);
                y0c = xrow[tn * D_IN];
            }

#pragma unroll 1
            for (int e = 0; e < EULER; ++e) {
                const int par = e & 1;
                short8 hB = __builtin_bit_cast(short8, *(const uint4v*)&hbuf[par][n16 * 20 + quad * 4]);
                float pacc = 0.f;
#pragma unroll
                for (int k = 0; k < 2; ++k) {
                    float4v a = b3v[k];
                    a = __builtin_amdgcn_mfma_f32_16x16x32_bf16(w3f[k], hB, a, 0, 0, 0);
                    pacc += w4v[k][0] * tanh_pre(a[0]) + w4v[k][1] * tanh_pre(a[1])
                          + w4v[k][2] * tanh_pre(a[2]) + w4v[k][3] * tanh_pre(a[3]);
                }
                pacc += __shfl_xor(pacc, 16, 64);
                pacc += __shfl_xor(pacc, 32, 64);
                if (lane < 16) pbuf[par][half][n16] = pacc;

                if (wave == 1) {
                    // merge previous global step's partials (visible since last barrier)
                    float m = pbuf[1 - par][0][n16] + pbuf[1 - par][1][n16];
                    if (e == 0) {
                        if (t > 0 && quad == 0)
                            out[(size_t)(b0 + n16) * T_STEPS + (t - 1)] =
                                prev_y0 + STEPF * prev_scl * (psum + m + (float)EULER * b4s);
                        psum = 0.f;
                        prev_scl = cur_scl; prev_y0 = cur_y0;
                    } else {
                        psum += m;
                    }
                }
                __syncthreads();
            } // e
        } // t
        __syncthreads();   // final partials (t=99,e=9) visible
        if (wave == 1) {
            float m = pbuf[1][0][n16] + pbuf[1][1][n16];   // step 999 parity = 1
            if (quad == 0)
                out[(size_t)(b0 + n16) * T_STEPS + (T_STEPS - 1)] =
                    prev_y0 + STEPF * prev_scl * (psum + m + (float)EULER * b4s);
        }
    }
}

extern "C" void kernel_launch(void* const* d_in, const int* in_sizes, int n_in,
                              void* d_out, int out_size, void* d_ws, size_t ws_size,
                              hipStream_t stream) {
    const float* dt = (const float*)d_in[0];
    const float* x  = (const float*)d_in[1];
    const float* W1 = (const float*)d_in[2];
    const float* b1 = (const float*)d_in[3];
    const float* W2 = (const float*)d_in[4];
    const float* b2 = (const float*)d_in[5];
    const float* W3 = (const float*)d_in[6];
    const float* b3 = (const float*)d_in[7];
    const float* W4 = (const float*)d_in[8];
    const float* b4 = (const float*)d_in[9];
    float* out = (float*)d_out;

    const int B = 8192;
    dim3 grid(B / 16), block(192);
    latode_kernel<<<grid, block, 0, stream>>>(dt, x, W1, b1, W2, b2, W3, b3, W4, b4, out);
}